// Round 1
// baseline (173.074 us; speedup 1.0000x reference)
//
#include <hip/hip_runtime.h>

// MessageFunc: out[e,o] = sum_i (relu-MLP(e_vw)[e] . W2[32o+i] + b2[32o+i]) * hw[e,i]
// hw[e,i] = h_w[b, (32*kn+i)//20], e = b*20+kn  (faithful expand+view scramble).
// Key trick: for fixed kn, (32*kn+i)//20 takes only 2-3 distinct values ->
// pre-sum W2 rows into W2g[kn][g][o][k] (g<3) and contract 96 cols instead of 1024.

typedef __bf16 bf16x8 __attribute__((ext_vector_type(8)));
typedef float  f32x4  __attribute__((ext_vector_type(4)));

#define NB       10000
#define NNEIGH   20
#define BM       64        // edges per block (all same kn)
#define NBT      157       // ceil(10000/64)

// ws layout (bytes)
#define WS_W0P   0         // bf16 [128][32]  (K padded 16->32 with zeros)   8192 B
#define WS_W1B   8192      // bf16 [128][128]                               32768 B
#define WS_W2G   40960     // bf16 [20][96][128] (96 = 3 groups * 32 o)     491520 B
#define WS_B2G   532480    // f32  [20][96]                                 7680 B
// total 540160 B required in d_ws

__device__ __forceinline__ unsigned short f2bf(float f) {
    unsigned int u = __float_as_uint(f);
    unsigned int r = (u + 0x7fffu + ((u >> 16) & 1u)) >> 16;
    return (unsigned short)r;
}
__device__ __forceinline__ unsigned int pack2(float a, float b) {
    return (unsigned int)f2bf(a) | ((unsigned int)f2bf(b) << 16);
}

// ---------------- prep: build bf16 weights + grouped W2 ----------------
__global__ __launch_bounds__(256) void prep_kernel(
    const float* __restrict__ W0, const float* __restrict__ W1,
    const float* __restrict__ W2, const float* __restrict__ b2,
    unsigned short* __restrict__ w0p, unsigned short* __restrict__ w1b,
    unsigned short* __restrict__ w2g, float* __restrict__ b2g)
{
    const int bx = blockIdx.x, tid = threadIdx.x;
    if (bx < 16) {
        // W2g: one thread per (o,k). gid in [0,4096)
        int gid = bx * 256 + tid;
        int o = gid >> 7, k = gid & 127;
        float rowv[32];
#pragma unroll
        for (int i = 0; i < 32; ++i) rowv[i] = W2[(size_t)(32 * o + i) * 128 + k];
#pragma unroll
        for (int kn = 0; kn < 20; ++kn) {
            int j0 = (32 * kn) / 20;
#pragma unroll
            for (int g = 0; g < 3; ++g) {
                int lo = 20 * (j0 + g) - 32 * kn;     if (lo < 0) lo = 0;
                int hi = 20 * (j0 + g + 1) - 32 * kn; if (hi > 32) hi = 32; if (hi < lo) hi = lo;
                float s = 0.f;
#pragma unroll
                for (int i = 0; i < 32; ++i) { if (i >= lo && i < hi) s += rowv[i]; }
                w2g[((size_t)(kn * 3 + g) * 32 + o) * 128 + k] = f2bf(s);
            }
        }
    } else if (bx == 16) {
        // b2g: 20*3*32 = 1920 entries
        for (int idx = tid; idx < 1920; idx += 256) {
            int kn = idx / 96, rem = idx - kn * 96;
            int g = rem >> 5, o = rem & 31;
            int j0 = (32 * kn) / 20;
            int lo = 20 * (j0 + g) - 32 * kn;     if (lo < 0) lo = 0;
            int hi = 20 * (j0 + g + 1) - 32 * kn; if (hi > 32) hi = 32; if (hi < lo) hi = lo;
            float s = 0.f;
            for (int i = lo; i < hi; ++i) s += b2[32 * o + i];
            b2g[idx] = s;
        }
    } else if (bx < 21) {
        // W0 padded: [128][32], zeros for k>=16
#pragma unroll
        for (int it = 0; it < 4; ++it) {
            int idx = (bx - 17) * 1024 + it * 256 + tid;   // [0,4096)
            int o = idx >> 5, kk = idx & 31;
            w0p[idx] = (kk < 16) ? f2bf(W0[o * 16 + kk]) : (unsigned short)0;
        }
    } else {
        // W1 cast: 16384 elements
#pragma unroll
        for (int it = 0; it < 4; ++it) {
            int idx = (bx - 21) * 1024 + it * 256 + tid;   // [0,16384)
            w1b[idx] = f2bf(W1[idx]);
        }
    }
}

// ---------------- main fused kernel ----------------
__global__ __launch_bounds__(256, 2) void msg_kernel(
    const float* __restrict__ h_w, const float* __restrict__ e_vw,
    const float* __restrict__ b0v, const float* __restrict__ b1v,
    const unsigned short* __restrict__ w0p, const unsigned short* __restrict__ w1b,
    const unsigned short* __restrict__ w2g, const float* __restrict__ b2g,
    float* __restrict__ out)
{
    __shared__ __align__(16) unsigned short sE[BM * 32];     // e tile, K padded to 32
    __shared__ __align__(16) unsigned short sX[BM * 128];    // x0 then x1 (in-place)
    __shared__ __align__(16) unsigned short sW1[128 * 128];
    __shared__ __align__(16) unsigned short sW2g[96 * 128];
    __shared__ float sB0[128], sB1[128], sB2G[96], sHW[BM * 3];

    const int tid = threadIdx.x;
    const int lane = tid & 63, w = tid >> 6;
    const int quad = lane >> 4, lq = lane & 15;
    const int kn = blockIdx.y, btile = blockIdx.x;
    const int bbase = btile * BM;
    const int j0 = (32 * kn) / 20;

    // ---- staging (global -> LDS) ----
    {   // e_vw tile: row r handled by threads 4r..4r+3, each a 16B chunk of the 64B row
        int r = tid >> 2, seg = tid & 3;
        int b = bbase + r;
        uint4 val = make_uint4(0u, 0u, 0u, 0u);
        if (seg < 2 && b < NB) {
            const float4* src = (const float4*)(e_vw + (size_t)(b * NNEIGH + kn) * 16 + seg * 8);
            float4 f0 = src[0], f1 = src[1];
            val = make_uint4(pack2(f0.x, f0.y), pack2(f0.z, f0.w),
                             pack2(f1.x, f1.y), pack2(f1.z, f1.w));
        }
        ((uint4*)sE)[r * 4 + seg] = val;
    }
    {   // W1: 32 KB
        const uint4* src = (const uint4*)w1b;
        uint4* dst = (uint4*)sW1;
        for (int i = tid; i < 2048; i += 256) dst[i] = src[i];
    }
    {   // W2g for this kn: 24 KB
        const uint4* src = (const uint4*)(w2g + (size_t)kn * 96 * 128);
        uint4* dst = (uint4*)sW2g;
        for (int i = tid; i < 1536; i += 256) dst[i] = src[i];
    }
    if (tid < 128) sB0[tid] = b0v[tid]; else sB1[tid - 128] = b1v[tid - 128];
    if (tid < 96)  sB2G[tid] = b2g[kn * 96 + tid];
    if (tid < BM * 3) {
        int r = tid / 3, g = tid - 3 * r;
        int b = bbase + r;
        int jv = j0 + g; if (jv > 31) jv = 31;
        sHW[tid] = (b < NB) ? h_w[b * 32 + jv] : 0.f;
    }
    __syncthreads();

    const int rbase = w * 16;   // this wave's 16-edge strip

    // ---- stage A: x0 = relu(E @ W0^T + b0), K=32 (padded) ----
    {
        bf16x8 af = *(const bf16x8*)&sE[(rbase + lq) * 32 + quad * 8];
#pragma unroll
        for (int ct = 0; ct < 8; ++ct) {
            bf16x8 bf = *(const bf16x8*)(w0p + (ct * 16 + lq) * 32 + quad * 8); // from L2
            f32x4 acc = {0.f, 0.f, 0.f, 0.f};
            acc = __builtin_amdgcn_mfma_f32_16x16x32_bf16(af, bf, acc, 0, 0, 0);
#pragma unroll
            for (int r2 = 0; r2 < 4; ++r2) {
                int row = rbase + quad * 4 + r2;
                int col = ct * 16 + lq;
                float v = acc[r2] + sB0[col];
                v = v > 0.f ? v : 0.f;
                sX[row * 128 + col] = f2bf(v);
            }
        }
    }

    // ---- stage B: x1 = relu(x0 @ W1^T + b1), K=128, in-place on sX ----
    {
        bf16x8 af[4];
#pragma unroll
        for (int ka = 0; ka < 4; ++ka)
            af[ka] = *(const bf16x8*)&sX[(rbase + lq) * 128 + ka * 32 + quad * 8];
        f32x4 accB[8];
#pragma unroll
        for (int ct = 0; ct < 8; ++ct) {
            f32x4 acc = {0.f, 0.f, 0.f, 0.f};
#pragma unroll
            for (int ka = 0; ka < 4; ++ka) {
                bf16x8 bf = *(const bf16x8*)&sW1[(ct * 16 + lq) * 128 + ka * 32 + quad * 8];
                acc = __builtin_amdgcn_mfma_f32_16x16x32_bf16(af[ka], bf, acc, 0, 0, 0);
            }
            accB[ct] = acc;
        }
        // write back (this wave only touches its own strip; DS ops are wave-ordered)
#pragma unroll
        for (int ct = 0; ct < 8; ++ct) {
#pragma unroll
            for (int r2 = 0; r2 < 4; ++r2) {
                int row = rbase + quad * 4 + r2;
                int col = ct * 16 + lq;
                float v = accB[ct][r2] + sB1[col];
                v = v > 0.f ? v : 0.f;
                sX[row * 128 + col] = f2bf(v);
            }
        }
    }

    // ---- stage C: G = x1 @ W2g^T (96 cols), then contract with h_w groups ----
    {
        bf16x8 af[4];
#pragma unroll
        for (int ka = 0; ka < 4; ++ka)
            af[ka] = *(const bf16x8*)&sX[(rbase + lq) * 128 + ka * 32 + quad * 8];
        f32x4 accC[6];
#pragma unroll
        for (int ct = 0; ct < 6; ++ct) {
            f32x4 acc = {0.f, 0.f, 0.f, 0.f};
#pragma unroll
            for (int ka = 0; ka < 4; ++ka) {
                bf16x8 bf = *(const bf16x8*)&sW2g[(ct * 16 + lq) * 128 + ka * 32 + quad * 8];
                acc = __builtin_amdgcn_mfma_f32_16x16x32_bf16(af[ka], bf, acc, 0, 0, 0);
            }
            accC[ct] = acc;
        }
        // epilogue: out[e,o] = sum_g hw[g] * (G[e, 32g+o] + b2g[g,o]);  col c = ct*16+lq = 32g+o
#pragma unroll
        for (int half = 0; half < 2; ++half) {
#pragma unroll
            for (int r2 = 0; r2 < 4; ++r2) {
                int row = rbase + quad * 4 + r2;     // edge row in block
                int b = bbase + row;
                int o = half * 16 + lq;
                float acc = 0.f;
#pragma unroll
                for (int g = 0; g < 3; ++g) {
                    float hw = sHW[row * 3 + g];
                    float m = accC[g * 2 + half][r2] + sB2G[g * 32 + o];
                    acc += hw * m;
                }
                if (b < NB)
                    out[(size_t)(b * NNEIGH + kn) * 32 + o] = acc;
            }
        }
    }
}

extern "C" void kernel_launch(void* const* d_in, const int* in_sizes, int n_in,
                              void* d_out, int out_size, void* d_ws, size_t ws_size,
                              hipStream_t stream)
{
    // setup_inputs order: h_v, h_w, e_vw, W0, b0, W1, b1, W2, b2  (all float32)
    const float* h_w = (const float*)d_in[1];
    const float* e_vw = (const float*)d_in[2];
    const float* W0 = (const float*)d_in[3];
    const float* b0 = (const float*)d_in[4];
    const float* W1 = (const float*)d_in[5];
    const float* b1 = (const float*)d_in[6];
    const float* W2 = (const float*)d_in[7];
    const float* b2 = (const float*)d_in[8];
    float* out = (float*)d_out;

    char* ws = (char*)d_ws;
    unsigned short* w0p = (unsigned short*)(ws + WS_W0P);
    unsigned short* w1b = (unsigned short*)(ws + WS_W1B);
    unsigned short* w2g = (unsigned short*)(ws + WS_W2G);
    float*          b2g = (float*)(ws + WS_B2G);

    prep_kernel<<<37, 256, 0, stream>>>(W0, W1, W2, b2, w0p, w1b, w2g, b2g);
    dim3 grid(NBT, 20);
    msg_kernel<<<grid, 256, 0, stream>>>(h_w, e_vw, b0, b1, w0p, w1b, w2g, b2g, out);
}

// Round 2
// 134.205 us; speedup vs baseline: 1.2896x; 1.2896x over previous
//
#include <hip/hip_runtime.h>

// MessageFunc: out[e,o] = sum_i (relu-MLP(e_vw)[e] . W2[32o+i] + b2[32o+i]) * hw[e,i]
// hw[e,i] = h_w[b, (32*kn+i)//20], e = b*20+kn. For fixed kn, (32*kn+i)//20 takes
// <=3 values -> grouped W2g[kn][g][o][k] (96 cols instead of 1024).
//
// R2 design: block = (kn, chunk); weights staged to LDS ONCE per block, then a
// barrier-free loop over btiles (sX is wave-private; DS ops are wave-ordered).
// All LDS rows padded to 136 halves (272B stride -> bank step 4 -> 2-way, free).
// W0 fragments + biases register-resident. e_vw A-frags loaded direct from global.

typedef __bf16 bf16x8 __attribute__((ext_vector_type(8)));
typedef float  f32x4  __attribute__((ext_vector_type(4)));

#define NB       10000
#define NNEIGH   20
#define PADH     136       // padded row length in halves (128 + 8)
#define NCHUNK   25        // blocks per kn; btile = chunk + 25*t

// ws layout (bytes)
#define WS_W0S   0         // bf16 [8][64][8] fragment-swizzled W0 (K padded to 32)  8192 B
#define WS_W1B   8192      // bf16 [128][128]                                       32768 B
#define WS_W2G   40960     // bf16 [20][96][128]                                   491520 B
#define WS_B2G   532480    // f32  [20][96]                                          7680 B

__device__ __forceinline__ unsigned short f2bf(float f) {
    unsigned int u = __float_as_uint(f);
    unsigned int r = (u + 0x7fffu + ((u >> 16) & 1u)) >> 16;
    return (unsigned short)r;
}
__device__ __forceinline__ unsigned int pack2(float a, float b) {
    return (unsigned int)f2bf(a) | ((unsigned int)f2bf(b) << 16);
}

// ---------------- prep: wide & parallel ----------------
__global__ __launch_bounds__(256) void prep_kernel(
    const float* __restrict__ W0, const float* __restrict__ W1,
    const float* __restrict__ W2, const float* __restrict__ b2,
    unsigned short* __restrict__ w0s, unsigned short* __restrict__ w1b,
    unsigned short* __restrict__ w2g, float* __restrict__ b2g)
{
    const int bx = blockIdx.x, tid = threadIdx.x;
    if (bx < 960) {
        // W2g: one thread per output element. gid = kn*12288 + c*128 + k
        int gid = bx * 256 + tid;
        int kn = gid / 12288, rem = gid % 12288;
        int c = rem >> 7, k = rem & 127;
        int g = c >> 5, o = c & 31;
        int j0 = (32 * kn) / 20;
        int lo = 20 * (j0 + g) - 32 * kn;     if (lo < 0) lo = 0;
        int hi = 20 * (j0 + g + 1) - 32 * kn; if (hi > 32) hi = 32;
        float s = 0.f;
        for (int i = lo; i < hi; ++i) s += W2[(size_t)(32 * o + i) * 128 + k];
        w2g[gid] = f2bf(s);
    } else if (bx == 960) {
        // b2g: 1920 entries
        for (int idx = tid; idx < 1920; idx += 256) {
            int kn = idx / 96, rem = idx - kn * 96;
            int g = rem >> 5, o = rem & 31;
            int j0 = (32 * kn) / 20;
            int lo = 20 * (j0 + g) - 32 * kn;     if (lo < 0) lo = 0;
            int hi = 20 * (j0 + g + 1) - 32 * kn; if (hi > 32) hi = 32;
            float s = 0.f;
            for (int i = lo; i < hi; ++i) s += b2[32 * o + i];
            b2g[idx] = s;
        }
    } else if (bx <= 962) {
        // W0 fragment-swizzled: w0s[ct][lane][j] = W0[(ct*16+lq)*16 + quad*8+j] (0 for k>=16)
        for (int i2 = tid; i2 < 2048; i2 += 256) {
            int idx = (bx - 961) * 2048 + i2;
            int ct = idx >> 9, lane = (idx >> 3) & 63, j = idx & 7;
            int lq = lane & 15, q = lane >> 4;
            int k = q * 8 + j;
            w0s[idx] = (k < 16) ? f2bf(W0[(ct * 16 + lq) * 16 + k]) : (unsigned short)0;
        }
    } else {
        // W1 cast: 16384 elements over 16 blocks
        int base = (bx - 963) * 1024;
        for (int i2 = tid; i2 < 1024; i2 += 256)
            w1b[base + i2] = f2bf(W1[base + i2]);
    }
}

// ---------------- main fused kernel ----------------
__global__ __launch_bounds__(256, 2) void msg_kernel(
    const float* __restrict__ h_w, const float* __restrict__ e_vw,
    const float* __restrict__ b0v, const float* __restrict__ b1v,
    const unsigned short* __restrict__ w0s, const unsigned short* __restrict__ w1b,
    const unsigned short* __restrict__ w2g, const float* __restrict__ b2g,
    float* __restrict__ out)
{
    __shared__ __align__(16) unsigned short sW1[128 * PADH];   // 34816 B
    __shared__ __align__(16) unsigned short sW2g[96 * PADH];   // 26112 B
    __shared__ __align__(16) unsigned short sX[64 * PADH];     // 17408 B

    const int tid = threadIdx.x;
    const int lane = tid & 63, w = tid >> 6;
    const int quad = lane >> 4, lq = lane & 15;
    const int kn = blockIdx.y, chunk = blockIdx.x;
    const int j0 = (32 * kn) / 20;

    // ---- stage weights once per block (padded rows: 17 uint4 pitch) ----
    {
        const uint4* src = (const uint4*)w1b;
        uint4* dst = (uint4*)sW1;
        for (int i = tid; i < 2048; i += 256) { int r = i >> 4, c = i & 15; dst[r * 17 + c] = src[i]; }
    }
    {
        const uint4* src = (const uint4*)(w2g + (size_t)kn * 96 * 128);
        uint4* dst = (uint4*)sW2g;
        for (int i = tid; i < 1536; i += 256) { int r = i >> 4, c = i & 15; dst[r * 17 + c] = src[i]; }
    }

    // ---- register-resident per-lane constants ----
    bf16x8 w0f[8];
#pragma unroll
    for (int ct = 0; ct < 8; ++ct)
        w0f[ct] = *(const bf16x8*)(w0s + (ct * 64 + lane) * 8);
    float b0r[8], b1r[8];
#pragma unroll
    for (int ct = 0; ct < 8; ++ct) {
        b0r[ct] = b0v[ct * 16 + lq];
        b1r[ct] = b1v[ct * 16 + lq];
    }
    float b2r[6];
#pragma unroll
    for (int i = 0; i < 6; ++i) {
        int g = i >> 1, half = i & 1;
        b2r[i] = b2g[kn * 96 + g * 32 + half * 16 + lq];
    }
    __syncthreads();   // the ONLY barrier

    const int rbase = w * 16;   // wave-private 16-edge strip of sX

    for (int btile = chunk; btile < 157; btile += NCHUNK) {
        const int bbase = btile * 64;
        const int rowE = bbase + rbase + lq;     // A-frag row (edge index)

        // ---- A-frag for stage A: direct from global (quads 0,1 real; 2,3 = zero pad) ----
        union { bf16x8 v; uint4 u; } A;
        A.u = make_uint4(0u, 0u, 0u, 0u);
        if (quad < 2 && rowE < NB) {
            const float4* p = (const float4*)(e_vw + ((size_t)rowE * NNEIGH + kn) * 16 + quad * 8);
            float4 f0 = p[0], f1 = p[1];
            A.u = make_uint4(pack2(f0.x, f0.y), pack2(f0.z, f0.w),
                             pack2(f1.x, f1.y), pack2(f1.z, f1.w));
        }

        // ---- h_w values for epilogue (issue early to hide latency) ----
        float hwv[4][3];
#pragma unroll
        for (int r2 = 0; r2 < 4; ++r2) {
            int b = bbase + rbase + quad * 4 + r2;
#pragma unroll
            for (int g = 0; g < 3; ++g) {
                int jv = j0 + g; if (jv > 31) jv = 31;
                hwv[r2][g] = (b < NB) ? h_w[b * 32 + jv] : 0.f;
            }
        }

        // ---- stage A: x0 = relu(E @ W0^T + b0), K=32 padded, weights in regs ----
#pragma unroll
        for (int ct = 0; ct < 8; ++ct) {
            f32x4 acc = {0.f, 0.f, 0.f, 0.f};
            acc = __builtin_amdgcn_mfma_f32_16x16x32_bf16(A.v, w0f[ct], acc, 0, 0, 0);
#pragma unroll
            for (int r2 = 0; r2 < 4; ++r2) {
                float v = acc[r2] + b0r[ct];
                v = v > 0.f ? v : 0.f;
                sX[(rbase + quad * 4 + r2) * PADH + ct * 16 + lq] = f2bf(v);
            }
        }

        // ---- stage B: x1 = relu(x0 @ W1^T + b1), K=128, in-place on sX ----
        {
            bf16x8 af[4];
#pragma unroll
            for (int ka = 0; ka < 4; ++ka)
                af[ka] = *(const bf16x8*)&sX[(rbase + lq) * PADH + ka * 32 + quad * 8];
#pragma unroll
            for (int ct = 0; ct < 8; ++ct) {
                f32x4 acc = {0.f, 0.f, 0.f, 0.f};
#pragma unroll
                for (int ka = 0; ka < 4; ++ka) {
                    bf16x8 bf = *(const bf16x8*)&sW1[(ct * 16 + lq) * PADH + ka * 32 + quad * 8];
                    acc = __builtin_amdgcn_mfma_f32_16x16x32_bf16(af[ka], bf, acc, 0, 0, 0);
                }
#pragma unroll
                for (int r2 = 0; r2 < 4; ++r2) {
                    float v = acc[r2] + b1r[ct];
                    v = v > 0.f ? v : 0.f;
                    sX[(rbase + quad * 4 + r2) * PADH + ct * 16 + lq] = f2bf(v);
                }
            }
        }

        // ---- stage C: G = x1 @ W2g^T (96 cols) + grouped h_w contraction ----
        {
            bf16x8 af[4];
#pragma unroll
            for (int ka = 0; ka < 4; ++ka)
                af[ka] = *(const bf16x8*)&sX[(rbase + lq) * PADH + ka * 32 + quad * 8];
            f32x4 accC[6];
#pragma unroll
            for (int ct = 0; ct < 6; ++ct) {
                f32x4 acc = {0.f, 0.f, 0.f, 0.f};
#pragma unroll
                for (int ka = 0; ka < 4; ++ka) {
                    bf16x8 bf = *(const bf16x8*)&sW2g[(ct * 16 + lq) * PADH + ka * 32 + quad * 8];
                    acc = __builtin_amdgcn_mfma_f32_16x16x32_bf16(af[ka], bf, acc, 0, 0, 0);
                }
                accC[ct] = acc;
            }
            // epilogue: out[e,o] = sum_g hw[g] * (G[e,32g+o] + b2g[g,o])
#pragma unroll
            for (int half = 0; half < 2; ++half) {
#pragma unroll
                for (int r2 = 0; r2 < 4; ++r2) {
                    int b = bbase + rbase + quad * 4 + r2;
                    float oval = 0.f;
#pragma unroll
                    for (int g = 0; g < 3; ++g)
                        oval += hwv[r2][g] * (accC[g * 2 + half][r2] + b2r[g * 2 + half]);
                    if (b < NB)
                        out[((size_t)b * NNEIGH + kn) * 32 + half * 16 + lq] = oval;
                }
            }
        }
    }
}

extern "C" void kernel_launch(void* const* d_in, const int* in_sizes, int n_in,
                              void* d_out, int out_size, void* d_ws, size_t ws_size,
                              hipStream_t stream)
{
    // setup_inputs order: h_v, h_w, e_vw, W0, b0, W1, b1, W2, b2  (all float32)
    const float* h_w = (const float*)d_in[1];
    const float* e_vw = (const float*)d_in[2];
    const float* W0 = (const float*)d_in[3];
    const float* b0 = (const float*)d_in[4];
    const float* W1 = (const float*)d_in[5];
    const float* b1 = (const float*)d_in[6];
    const float* W2 = (const float*)d_in[7];
    const float* b2 = (const float*)d_in[8];
    float* out = (float*)d_out;

    char* ws = (char*)d_ws;
    unsigned short* w0s = (unsigned short*)(ws + WS_W0S);
    unsigned short* w1b = (unsigned short*)(ws + WS_W1B);
    unsigned short* w2g = (unsigned short*)(ws + WS_W2G);
    float*          b2g = (float*)(ws + WS_B2G);

    prep_kernel<<<979, 256, 0, stream>>>(W0, W1, W2, b2, w0s, w1b, w2g, b2g);
    dim3 grid(NCHUNK, 20);
    msg_kernel<<<grid, 256, 0, stream>>>(h_w, e_vw, b0, b1, w0s, w1b, w2g, b2g, out);
}